// Round 1
// baseline (424.077 us; speedup 1.0000x reference)
//
#include <hip/hip_runtime.h>

// Problem constants (from reference):
//   B=8, S=4, L=512, H=768  -> hidden (8, 2048, 768) fp32
//   N_SPANS=4096, T_MAX=16, N_PAIRS=16384
//   reprs[s] = [first(768) | mean(768) | last(768)]  (2304 floats)
//   out[p]   = [reprs[pair_i[p]] | reprs[pair_j[p]]] (4608 floats)
//
// Strategy: one block per pair, 192 threads = 768/4 float4 columns.
// hidden (50 MB) lives in L3, so the redundant per-pair gather (vs a
// two-phase reprs workspace) costs only cache reads, and we avoid a
// 38 MB workspace write+read round trip. Output writes (302 MB) are the
// HBM bound.

#define SPAN_H    768
#define SPAN_HF4  192          // H / 4
#define SPAN_TMAX 16
#define SPAN_SL   2048         // S * L

__global__ __launch_bounds__(192)
void span_pooler_40097814675703_kernel(
    const float4* __restrict__ hidden,    // (B, SL, HF4) as float4
    const int*    __restrict__ span_doc,  // (N_SPANS)
    const int*    __restrict__ span_tok,  // (N_SPANS, TMAX)
    const int*    __restrict__ span_len,  // (N_SPANS)
    const int*    __restrict__ pair_i,    // (N_PAIRS)
    const int*    __restrict__ pair_j,    // (N_PAIRS)
    float4*       __restrict__ out)       // (N_PAIRS, 1152) as float4
{
    const int p = blockIdx.x;
    const int c = threadIdx.x;            // 0..191, one float4 column of H

    const int si = pair_i[p];             // block-uniform -> scalar loads
    const int sj = pair_j[p];

    float4* orow = out + (size_t)p * 1152;

    #pragma unroll
    for (int side = 0; side < 2; ++side) {
        const int s   = side ? sj : si;
        const int doc = span_doc[s];
        const int len = span_len[s];      // uniform per block: no divergence
        const int* toks = span_tok + s * SPAN_TMAX;
        const float4* base = hidden + (size_t)doc * (SPAN_SL * SPAN_HF4);

        float4 first = make_float4(0.f, 0.f, 0.f, 0.f);
        float4 last  = make_float4(0.f, 0.f, 0.f, 0.f);
        float sx = 0.f, sy = 0.f, sz = 0.f, sw = 0.f;

        for (int t = 0; t < len; ++t) {
            const float4 v = base[(size_t)toks[t] * SPAN_HF4 + c];
            if (t == 0) first = v;
            last = v;
            sx += v.x; sy += v.y; sz += v.z; sw += v.w;
        }

        const float inv = 1.0f / (float)len;
        const float4 mean = make_float4(sx * inv, sy * inv, sz * inv, sw * inv);

        float4* o = orow + side * 576;    // 576 float4 = 2304 floats per side
        o[c]       = first;
        o[192 + c] = mean;
        o[384 + c] = last;
    }
}

extern "C" void kernel_launch(void* const* d_in, const int* in_sizes, int n_in,
                              void* d_out, int out_size, void* d_ws, size_t ws_size,
                              hipStream_t stream) {
    const float4* hidden  = (const float4*)d_in[0];
    const int* span_doc   = (const int*)d_in[1];
    const int* span_tok   = (const int*)d_in[2];
    const int* span_len   = (const int*)d_in[3];
    const int* pair_i     = (const int*)d_in[4];
    const int* pair_j     = (const int*)d_in[5];
    float4* out           = (float4*)d_out;

    const int n_pairs = in_sizes[4];      // 16384

    span_pooler_40097814675703_kernel<<<n_pairs, 192, 0, stream>>>(
        hidden, span_doc, span_tok, span_len, pair_i, pair_j, out);
}

// Round 2
// 390.606 us; speedup vs baseline: 1.0857x; 1.0857x over previous
//
#include <hip/hip_runtime.h>

// Problem constants (from reference):
//   B=8, S=4, L=512, H=768  -> hidden (8, 2048, 768) fp32 (50 MB, L3-resident)
//   N_SPANS=4096, T_MAX=16, N_PAIRS=16384
//   reprs[s] = [first(768) | mean(768) | last(768)]  (2304 floats = 576 float4)
//   out[p]   = [reprs[pair_i[p]] | reprs[pair_j[p]]] (4608 floats = 1152 float4)
//
// Two-phase:
//   Phase 1: 4096 blocks x 192 threads -> reprs into d_ws (37.75 MB).
//            Fully unrolled over T_MAX with clamped token index: 16 independent
//            L3-hit loads in flight, branch-free (len is block-uniform anyway).
//   Phase 2: streaming gather-copy, 302 MB coalesced writes (the HBM bound),
//            reads hit L3 (reprs = 38 MB).

#define SPAN_HF4  192          // H / 4 float4s
#define SPAN_TMAX 16
#define SPAN_SL   2048         // S * L
#define REPR_F4   576          // 3 * 192 float4 per span
#define OUT_F4    1152         // 2 * 576 float4 per pair

__global__ __launch_bounds__(192)
void span_reprs_kernel(
    const float4* __restrict__ hidden,    // (B, SL, HF4)
    const int*    __restrict__ span_doc,
    const int*    __restrict__ span_tok,  // (N_SPANS, TMAX)
    const int*    __restrict__ span_len,
    float4*       __restrict__ reprs)     // (N_SPANS, 576)
{
    const int s = blockIdx.x;
    const int c = threadIdx.x;            // 0..191

    const int doc = span_doc[s];          // block-uniform
    const int len = span_len[s];
    const int* toks = span_tok + s * SPAN_TMAX;
    const float4* base = hidden + (size_t)doc * (SPAN_SL * SPAN_HF4);

    float4 first = make_float4(0.f, 0.f, 0.f, 0.f);
    float4 last  = make_float4(0.f, 0.f, 0.f, 0.f);
    float sx = 0.f, sy = 0.f, sz = 0.f, sw = 0.f;

    // Clamp index: loads beyond len-1 reload token len-1 (valid addr, L3-hit).
    // => 16 unconditional independent loads; `last` falls out for free.
    #pragma unroll
    for (int t = 0; t < SPAN_TMAX; ++t) {
        const int tc = (t < len) ? t : (len - 1);
        const float4 v = base[(size_t)toks[tc] * SPAN_HF4 + c];
        if (t == 0) first = v;            // uniform, compile-time peel
        last = v;
        const float m = (t < len) ? 1.f : 0.f;
        sx += v.x * m; sy += v.y * m; sz += v.z * m; sw += v.w * m;
    }

    const float inv = 1.0f / (float)len;
    float4* r = reprs + (size_t)s * REPR_F4;
    r[c]       = first;
    r[SPAN_HF4 + c] = make_float4(sx * inv, sy * inv, sz * inv, sw * inv);
    r[2 * SPAN_HF4 + c] = last;
}

__global__ __launch_bounds__(192)
void span_pairs_kernel(
    const float4* __restrict__ reprs,     // (N_SPANS, 576)
    const int*    __restrict__ pair_i,
    const int*    __restrict__ pair_j,
    float4*       __restrict__ out,       // (N_PAIRS, 1152)
    int n_pairs)
{
    const int c = threadIdx.x;            // 0..191
    for (int p = blockIdx.x; p < n_pairs; p += gridDim.x) {
        const int pi = pair_i[p];
        const int pj = pair_j[p];
        const float4* ri = reprs + (size_t)pi * REPR_F4;
        const float4* rj = reprs + (size_t)pj * REPR_F4;
        float4* o = out + (size_t)p * OUT_F4;

        // 6 independent loads, then 6 coalesced stores (3 KB/wave-instr).
        const float4 a0 = ri[c];
        const float4 a1 = ri[SPAN_HF4 + c];
        const float4 a2 = ri[2 * SPAN_HF4 + c];
        const float4 b0 = rj[c];
        const float4 b1 = rj[SPAN_HF4 + c];
        const float4 b2 = rj[2 * SPAN_HF4 + c];
        o[c]                 = a0;
        o[SPAN_HF4 + c]      = a1;
        o[2 * SPAN_HF4 + c]  = a2;
        o[3 * SPAN_HF4 + c]  = b0;
        o[4 * SPAN_HF4 + c]  = b1;
        o[5 * SPAN_HF4 + c]  = b2;
    }
}

// Fallback single kernel (only used if ws_size is too small for reprs).
__global__ __launch_bounds__(192)
void span_fused_kernel(
    const float4* __restrict__ hidden,
    const int*    __restrict__ span_doc,
    const int*    __restrict__ span_tok,
    const int*    __restrict__ span_len,
    const int*    __restrict__ pair_i,
    const int*    __restrict__ pair_j,
    float4*       __restrict__ out)
{
    const int p = blockIdx.x;
    const int c = threadIdx.x;
    const int si = pair_i[p];
    const int sj = pair_j[p];
    float4* orow = out + (size_t)p * OUT_F4;

    #pragma unroll
    for (int side = 0; side < 2; ++side) {
        const int s   = side ? sj : si;
        const int doc = span_doc[s];
        const int len = span_len[s];
        const int* toks = span_tok + s * SPAN_TMAX;
        const float4* base = hidden + (size_t)doc * (SPAN_SL * SPAN_HF4);

        float4 first = make_float4(0.f, 0.f, 0.f, 0.f);
        float4 last  = make_float4(0.f, 0.f, 0.f, 0.f);
        float sx = 0.f, sy = 0.f, sz = 0.f, sw = 0.f;
        #pragma unroll
        for (int t = 0; t < SPAN_TMAX; ++t) {
            const int tc = (t < len) ? t : (len - 1);
            const float4 v = base[(size_t)toks[tc] * SPAN_HF4 + c];
            if (t == 0) first = v;
            last = v;
            const float m = (t < len) ? 1.f : 0.f;
            sx += v.x * m; sy += v.y * m; sz += v.z * m; sw += v.w * m;
        }
        const float inv = 1.0f / (float)len;
        float4* o = orow + side * REPR_F4;
        o[c]                = first;
        o[SPAN_HF4 + c]     = make_float4(sx * inv, sy * inv, sz * inv, sw * inv);
        o[2 * SPAN_HF4 + c] = last;
    }
}

extern "C" void kernel_launch(void* const* d_in, const int* in_sizes, int n_in,
                              void* d_out, int out_size, void* d_ws, size_t ws_size,
                              hipStream_t stream) {
    const float4* hidden  = (const float4*)d_in[0];
    const int* span_doc   = (const int*)d_in[1];
    const int* span_tok   = (const int*)d_in[2];
    const int* span_len   = (const int*)d_in[3];
    const int* pair_i     = (const int*)d_in[4];
    const int* pair_j     = (const int*)d_in[5];
    float4* out           = (float4*)d_out;

    const int n_spans = in_sizes[1];      // 4096
    const int n_pairs = in_sizes[4];      // 16384
    const size_t reprs_bytes = (size_t)n_spans * REPR_F4 * sizeof(float4);

    if (ws_size >= reprs_bytes) {
        float4* reprs = (float4*)d_ws;
        span_reprs_kernel<<<n_spans, 192, 0, stream>>>(
            hidden, span_doc, span_tok, span_len, reprs);
        // 4096 blocks, 4 pairs each: grid-stride amortizes block setup.
        span_pairs_kernel<<<4096, 192, 0, stream>>>(
            reprs, pair_i, pair_j, out, n_pairs);
    } else {
        span_fused_kernel<<<n_pairs, 192, 0, stream>>>(
            hidden, span_doc, span_tok, span_len, pair_i, pair_j, out);
    }
}